// Round 3
// baseline (1646.575 us; speedup 1.0000x reference)
//
#include <hip/hip_runtime.h>
#include <hip/hip_bf16.h>
#include <cstdint>

// sincKAN: 3 layers. B=1024, features 256->512->512->256, LEN_H=2, DEGREE+1=65.
// Kaug = fi*131 (per input i: h0 d0..64 | h1 d0..64 | skip slot = x_i).
// Split-bf16 (hi/lo): acc += Ahi*Bhi + Ahi*Blo + Alo*Bhi (layers 0,1);
// layer 2 hi-only. PASSED R8 @ 2.125, R10 @ 2.125 (963us).
// R10: 256x256-tile 3-phase counted-vmcnt GEMM (8 waves 2Mx4N, BK=32,
// 128KiB LDS dbuf, raw s_barrier + CFENCE, vmcnt(6)/(6)/(4), setprio).
// R11: software-pipeline ds_reads one phase ahead. R10 serialized the LDS
// pipe (192 b128/step ~3.1-3.8k cyc) against the MFMA pipe (~3.1k cyc/SIMD):
// each phase read frags -> lgkmcnt(0) -> MFMA. Now each phase, AFTER its
// data-guarantee barrier, issues the NEXT phase's fragment reads and then
// runs the current cluster -- reads complete under the MFMA shadow:
//   A: gl AHn,BHn; vmcnt(6); bar; read bl(cur);       MFMA hh(ah,bh); bar
//   B: gl BLn;     vmcnt(6); bar; read al(cur);       MFMA hl(ah,bl); bar
//   C: gl ALn;     vmcnt(4); bar; read ah,bh (nxt);   MFMA lh(al,bh); bar
// vmcnt ledger identical to R10 (proven); compiler emits precise counted
// lgkmcnt for each cluster's operands (issued a full phase earlier).
// Layer 2 keeps the proven 128x128 one-pass kernel.

#define PI_F 3.14159265358979323846f

typedef float floatx4 __attribute__((ext_vector_type(4)));
typedef __bf16 bf16x8 __attribute__((ext_vector_type(8)));

// global -> LDS direct DMA, 16B per lane (lane-contiguous dest, per m104/m108).
#define GLOAD_LDS16(gp, lp)                                                    \
  __builtin_amdgcn_global_load_lds(                                            \
      (const __attribute__((address_space(1))) void*)(uintptr_t)(const void*)(gp), \
      (__attribute__((address_space(3))) void*)(uint32_t)(uintptr_t)(void*)(lp),   \
      16, 0, 0)

// compiler-only fence: no instruction emitted, pins memory-op order across
// raw s_barrier (which is NOT an IR-level memory barrier).
#define CFENCE() asm volatile("" ::: "memory")

// ---------------------------------------------------------------------------
// repack body: coeffs (fi,fo,2,65) + alpha (fi,fo) -> Bhi/Blo (fo x Kaug)
static __device__ __forceinline__ void repack_body(
    const float* __restrict__ coeffs, const float* __restrict__ alpha,
    ushort* __restrict__ Bhi, ushort* __restrict__ Blo,
    int fo, int Kaug, int writeLo, int idx, int tid)
{
  int nchunksK = Kaug >> 8;
  int o     = idx / nchunksK;
  int chunk = idx - o * nchunksK;
  int r = chunk * 256 + tid;
  int i = r / 131;
  int j = r - i * 131;
  float v;
  if (j == 130) {
    v = alpha[(size_t)i * fo + o];
  } else {
    int h1 = (j >= 65) ? 1 : 0;
    int d  = j - (h1 ? 65 : 0);
    v = coeffs[(((size_t)i * fo + o) * 2 + h1) * 65 + d];
  }
  __hip_bfloat16 hb = __float2bfloat16(v);
  Bhi[(size_t)o * Kaug + r] = *(ushort*)&hb;
  if (writeLo) {
    __hip_bfloat16 lb = __float2bfloat16(v - __bfloat162float(hb));
    Blo[(size_t)o * Kaug + r] = *(ushort*)&lb;
  }
}

// all-3-layers repack in one dispatch (allB mode)
__global__ __launch_bounds__(256) void repack_all(
    const float* c0, const float* a0, ushort* h0, ushort* l0,
    const float* c1, const float* a1, ushort* h1, ushort* l1,
    const float* c2, const float* a2, ushort* h2,
    int fo0, int fo1, int fo2, int K0, int K1, int K2, int nb0, int nb01)
{
  int b = blockIdx.x, tid = threadIdx.x;
  if (b < nb0)        repack_body(c0, a0, h0, l0, fo0, K0, 1, b,        tid);
  else if (b < nb01)  repack_body(c1, a1, h1, l1, fo1, K1, 1, b - nb0,  tid);
  else                repack_body(c2, a2, h2, 0,  fo2, K2, 0, b - nb01, tid);
}

// per-layer repack (fallback mode)
__global__ __launch_bounds__(256) void repack_kernel(
    const float* __restrict__ coeffs, const float* __restrict__ alpha,
    ushort* __restrict__ Bhi, ushort* __restrict__ Blo,
    int fo, int Kaug, int writeLo)
{
  repack_body(coeffs, alpha, Bhi, Blo, fo, Kaug, writeLo,
              blockIdx.x + blockIdx.y * gridDim.x, threadIdx.x);
}

// ---------------------------------------------------------------------------
// act: Xin (MB x fi) fp32 -> Ahi/Alo (MB x Kaug) bf16 pair, chunk-local.
__global__ __launch_bounds__(256) void act_kernel(
    const float* __restrict__ Xin, ushort* __restrict__ Ahi,
    ushort* __restrict__ Alo, int first, int writeLo)
{
  __shared__ float sm[256][5];
  int tid = threadIdx.x;
  int p0  = blockIdx.x * 256;   // first (b,i) pair of this block (chunk-local)
  {
    float x  = Xin[p0 + tid];
    float t  = first ? tanhf(x) : x;   // layer-0 normalizer
    float xa = tanhf(t);
    float z0 = 4.0f * xa, z1 = 8.0f * xa;   // exact (pow2 scale, h=1/4,1/8)
    float n0 = rintf(z0), n1 = rintf(z1);
    float s0 = sinf(PI_F * (z0 - n0)) * (1.0f / PI_F);
    float s1 = sinf(PI_F * (z1 - n1)) * (1.0f / PI_F);
    if (((int)n0) & 1) s0 = -s0;
    if (((int)n1) & 1) s1 = -s1;
    sm[tid][0] = t;
    sm[tid][1] = z0;
    sm[tid][2] = s0;
    sm[tid][3] = z1;
    sm[tid][4] = s1;
  }
  __syncthreads();
  size_t base = (size_t)p0 * 131;           // multiple of 4 (256*131*blk)
  for (int e4 = tid; e4 < 64 * 131; e4 += 256) {   // 131*256/4 quads
    int f0 = e4 * 4;
    ushort4 hv, lv;
#pragma unroll
    for (int u = 0; u < 4; ++u) {
      int f  = f0 + u;
      int li = f / 131;
      int j  = f - li * 131;
      float t = sm[li][0];
      bool h1 = (j >= 65);
      int d   = h1 ? (j - 65) : j;
      float z = h1 ? sm[li][3] : sm[li][1];
      float s = h1 ? sm[li][4] : sm[li][2];
      int kk  = d - 32;
      float den = z + (float)kk;
      float v = __fdividef(s, den);
      if (kk & 1) v = -v;
      if (den == 0.0f) v = 1.0f;   // sinc(0) = 1 (sign: n=-kk, parity cancels)
      if (j == 130)    v = t;      // skip-connection slot
      __hip_bfloat16 hb = __float2bfloat16(v);
      __hip_bfloat16 lb = __float2bfloat16(v - __bfloat162float(hb));
      ((ushort*)&hv)[u] = *(ushort*)&hb;
      ((ushort*)&lv)[u] = *(ushort*)&lb;
    }
    *(ushort4*)(Ahi + base + f0) = hv;
    if (writeLo) *(ushort4*)(Alo + base + f0) = lv;
  }
}

// ---------------------------------------------------------------------------
// gemm one-pass 128x128 (kept for layer 2 / fallback): see R8 notes.
__global__ __launch_bounds__(256, 4) void gemm_bf16_onepass(
    const ushort* __restrict__ Ahi, const ushort* __restrict__ Alo,
    const ushort* __restrict__ Bhi, const ushort* __restrict__ Blo,
    float* __restrict__ Cpart,              // splitk x MB x N
    int N, int Kaug, int T, int splitk, int tilesN, int MBN, int nterms)
{
  __shared__ __align__(16) ushort AsH[128 * 32];
  __shared__ __align__(16) ushort AsL[128 * 32];
  __shared__ __align__(16) ushort BsH[128 * 32];
  __shared__ __align__(16) ushort BsL[128 * 32];

  int bx    = blockIdx.x;
  int split = bx % splitk;
  int tile  = bx / splitk;
  int tm = tile / tilesN;
  int tn = tile - tm * tilesN;
  int s0 = (int)(((long long)split * T) / splitk);
  int s1 = (int)(((long long)(split + 1) * T) / splitk);

  int tid  = threadIdx.x;
  int lane = tid & 63;
  int wave = tid >> 6;
  int wm = (wave >> 1) * 64;
  int wn = (wave & 1) * 64;

  floatx4 acc[4][4];
#pragma unroll
  for (int i = 0; i < 4; i++)
#pragma unroll
    for (int j = 0; j < 4; j++) acc[i][j] = floatx4{0.f, 0.f, 0.f, 0.f};

  const ushort* AgH = Ahi + (size_t)tm * 128 * Kaug;
  const ushort* AgL = Alo + (size_t)tm * 128 * Kaug;
  const ushort* BgH = Bhi + (size_t)tn * 128 * Kaug;
  const ushort* BgL = Blo + (size_t)tn * 128 * Kaug;

  int rsub = lane & 15;
  int qc   = lane >> 4;
  int aoff[4], boff[4];
#pragma unroll
  for (int t = 0; t < 4; ++t) {
    int ra = wm + t * 16 + rsub;
    aoff[t] = (ra * 4 + (qc ^ (ra & 3) ^ ((ra >> 2) & 3))) * 8;
    int rb = wn + t * 16 + rsub;
    boff[t] = (rb * 4 + (qc ^ (rb & 3) ^ ((rb >> 2) & 3))) * 8;
  }

  for (int s = s0; s < s1; ++s) {
    int k0 = s * 32;
#pragma unroll
    for (int r = 0; r < 2; ++r) {           // 512 chunks per tile, 2 iters
      int c   = tid + 256 * r;
      int row = c >> 2;
      int cc  = c & 3;
      int kcg = cc ^ (row & 3) ^ ((row >> 2) & 3);
      size_t goff = (size_t)row * Kaug + k0 + kcg * 8;
      GLOAD_LDS16(AgH + goff, &AsH[c * 8]);
      GLOAD_LDS16(BgH + goff, &BsH[c * 8]);
      if (nterms > 1) {
        GLOAD_LDS16(AgL + goff, &AsL[c * 8]);
        GLOAD_LDS16(BgL + goff, &BsL[c * 8]);
      }
    }
    __syncthreads();

    bf16x8 ah[4], bh[4];
#pragma unroll
    for (int t = 0; t < 4; ++t) ah[t] = *(const bf16x8*)&AsH[aoff[t]];
#pragma unroll
    for (int t = 0; t < 4; ++t) bh[t] = *(const bf16x8*)&BsH[boff[t]];
#pragma unroll
    for (int i = 0; i < 4; ++i)
#pragma unroll
      for (int j = 0; j < 4; ++j)
        acc[i][j] = __builtin_amdgcn_mfma_f32_16x16x32_bf16(
            ah[i], bh[j], acc[i][j], 0, 0, 0);

    if (nterms > 1) {
      bf16x8 bl[4];
#pragma unroll
      for (int t = 0; t < 4; ++t) bl[t] = *(const bf16x8*)&BsL[boff[t]];
#pragma unroll
      for (int i = 0; i < 4; ++i)
#pragma unroll
        for (int j = 0; j < 4; ++j)
          acc[i][j] = __builtin_amdgcn_mfma_f32_16x16x32_bf16(
              ah[i], bl[j], acc[i][j], 0, 0, 0);
      bf16x8 al[4];
#pragma unroll
      for (int t = 0; t < 4; ++t) al[t] = *(const bf16x8*)&AsL[aoff[t]];
#pragma unroll
      for (int i = 0; i < 4; ++i)
#pragma unroll
        for (int j = 0; j < 4; ++j)
          acc[i][j] = __builtin_amdgcn_mfma_f32_16x16x32_bf16(
              al[i], bh[j], acc[i][j], 0, 0, 0);
    }
    __syncthreads();
  }

  float* Cp = Cpart + (size_t)split * MBN;
  int mrow0 = tm * 128 + wm + (lane >> 4) * 4;
  int ncol  = tn * 128 + wn + (lane & 15);
#pragma unroll
  for (int i = 0; i < 4; ++i) {
#pragma unroll
    for (int r = 0; r < 4; ++r) {
      int m = mrow0 + i * 16 + r;
      float* dst = Cp + (size_t)m * N + ncol;
#pragma unroll
      for (int j = 0; j < 4; ++j) dst[j * 16] = acc[i][j][r];
    }
  }
}

// ---------------------------------------------------------------------------
// R11: 256x256-tile, 3-phase counted-vmcnt GEMM, ds_reads pipelined one
// phase ahead (see header comment). 512 threads = 8 waves (2M x 4N),
// per-wave 128x64 output, BK=32. LDS: 4 operand tiles x 2 buffers = 128 KiB.
__global__ __launch_bounds__(512, 2) void gemm256_nt3(
    const ushort* __restrict__ Ahi, const ushort* __restrict__ Alo,
    const ushort* __restrict__ Bhi, const ushort* __restrict__ Blo,
    float* __restrict__ Cpart,              // splitk x MB x N
    int N, int Kaug, int T, int splitk, int tilesN, int MBN)
{
  __shared__ __align__(16) ushort AsH[2][8192];
  __shared__ __align__(16) ushort AsL[2][8192];
  __shared__ __align__(16) ushort BsH[2][8192];
  __shared__ __align__(16) ushort BsL[2][8192];

  const int bx    = blockIdx.x;
  const int split = bx % splitk;            // split = bx%sk: same-split tile
  const int tile  = bx / splitk;            // group co-lands on one XCD (sk%8==0)
  const int tm = tile / tilesN;
  const int tn = tile - tm * tilesN;
  const int s0 = (int)(((long long)split * T) / splitk);
  const int s1 = (int)(((long long)(split + 1) * T) / splitk);

  const int tid  = threadIdx.x;
  const int lane = tid & 63;
  const int wave = tid >> 6;
  const int wm = (wave >> 2) * 128;
  const int wn = (wave & 3) * 64;

  floatx4 acc[8][4];
#pragma unroll
  for (int i = 0; i < 8; ++i)
#pragma unroll
    for (int j = 0; j < 4; ++j) acc[i][j] = floatx4{0.f, 0.f, 0.f, 0.f};

  const ushort* AgH = Ahi + (size_t)tm * 256 * Kaug;
  const ushort* AgL = Alo + (size_t)tm * 256 * Kaug;
  const ushort* BgH = Bhi + (size_t)tn * 256 * Kaug;
  const ushort* BgL = Blo + (size_t)tn * 256 * Kaug;

  // staging: thread covers chunks c0=tid, c1=tid+512 of 1024 16B-chunks per
  // operand tile. LDS dest linear (lane-contiguous); global source
  // pre-swizzled with x(row) = (row&3)^((row>>2)&3)  (proven in R8 kernel).
  const int c0 = tid, c1 = tid + 512;
  const int r0c = c0 >> 2, q0c = c0 & 3;
  const int r1c = c1 >> 2, q1c = c1 & 3;
  const size_t g0 = (size_t)r0c * Kaug + (size_t)((q0c ^ (r0c & 3) ^ ((r0c >> 2) & 3)) * 8);
  const size_t g1 = (size_t)r1c * Kaug + (size_t)((q1c ^ (r1c & 3) ^ ((r1c >> 2) & 3)) * 8);
  const int d0 = c0 * 8, d1 = c1 * 8;       // LDS ushort offsets

  // MFMA fragment LDS offsets (ushort units): row ra, k-chunk qc, swizzled.
  const int rsub = lane & 15;
  const int qc   = lane >> 4;
  int aoff[8], boff[4];
#pragma unroll
  for (int t = 0; t < 8; ++t) {
    int ra = wm + t * 16 + rsub;
    aoff[t] = (ra * 4 + (qc ^ (ra & 3) ^ ((ra >> 2) & 3))) * 8;
  }
#pragma unroll
  for (int t = 0; t < 4; ++t) {
    int rb = wn + t * 16 + rsub;
    boff[t] = (rb * 4 + (qc ^ (rb & 3) ^ ((rb >> 2) & 3))) * 8;
  }

  { // prologue: stage tile s0 into buffer 0 (issue order AH,BH,BL,AL)
    const int k0 = s0 * 32;
    GLOAD_LDS16(AgH + g0 + k0, &AsH[0][d0]);
    GLOAD_LDS16(AgH + g1 + k0, &AsH[0][d1]);
    GLOAD_LDS16(BgH + g0 + k0, &BsH[0][d0]);
    GLOAD_LDS16(BgH + g1 + k0, &BsH[0][d1]);
    GLOAD_LDS16(BgL + g0 + k0, &BsL[0][d0]);
    GLOAD_LDS16(BgL + g1 + k0, &BsL[0][d1]);
    GLOAD_LDS16(AgL + g0 + k0, &AsL[0][d0]);
    GLOAD_LDS16(AgL + g1 + k0, &AsL[0][d1]);
  }
  asm volatile("s_waitcnt vmcnt(4)" ::: "memory");   // AH,BH landed (own)
  __builtin_amdgcn_s_barrier();                      // ... and all waves'
  CFENCE();

  // prologue fragment reads: ah,bh for step s0 (consumed at phase A/B/C)
  bf16x8 ah[8], bh[4], bl[4], al[8];
#pragma unroll
  for (int t = 0; t < 8; ++t) ah[t] = *(const bf16x8*)&AsH[0][aoff[t]];
#pragma unroll
  for (int t = 0; t < 4; ++t) bh[t] = *(const bf16x8*)&BsH[0][boff[t]];

  int cur = 0;
  for (int s = s0; s < s1; ++s) {
    const int  nxt     = cur ^ 1;
    const bool notlast = (s + 1 < s1);
    const int  kn      = (s + 1) * 32;

    // ---------------- phase A: MFMA hh = Ahi x Bhi ----------------
    if (notlast) {
      GLOAD_LDS16(AgH + g0 + kn, &AsH[nxt][d0]);
      GLOAD_LDS16(AgH + g1 + kn, &AsH[nxt][d1]);
      GLOAD_LDS16(BgH + g0 + kn, &BsH[nxt][d0]);
      GLOAD_LDS16(BgH + g1 + kn, &BsH[nxt][d1]);
      asm volatile("s_waitcnt vmcnt(6)" ::: "memory");  // curr BL done (own)
    } else {
      asm volatile("s_waitcnt vmcnt(2)" ::: "memory");  // curr BL done (tail)
    }
    __builtin_amdgcn_s_barrier();                       // all waves' BL done
    CFENCE();
    // issue next-phase reads: bl from cur (hidden under hh cluster)
#pragma unroll
    for (int t = 0; t < 4; ++t) bl[t] = *(const bf16x8*)&BsL[cur][boff[t]];
    __builtin_amdgcn_s_setprio(1);
#pragma unroll
    for (int i = 0; i < 8; ++i)
#pragma unroll
      for (int j = 0; j < 4; ++j)
        acc[i][j] = __builtin_amdgcn_mfma_f32_16x16x32_bf16(
            ah[i], bh[j], acc[i][j], 0, 0, 0);
    __builtin_amdgcn_s_setprio(0);
    __builtin_amdgcn_s_barrier();
    CFENCE();

    // ---------------- phase B: MFMA hl = Ahi x Blo ----------------
    if (notlast) {
      GLOAD_LDS16(BgL + g0 + kn, &BsL[nxt][d0]);
      GLOAD_LDS16(BgL + g1 + kn, &BsL[nxt][d1]);
      asm volatile("s_waitcnt vmcnt(6)" ::: "memory");  // curr AL done (own)
    } else {
      asm volatile("s_waitcnt vmcnt(0)" ::: "memory");  // curr AL done (tail)
    }
    __builtin_amdgcn_s_barrier();                       // all waves' AL done
    CFENCE();
    // issue next-phase reads: al from cur (hidden under hl cluster)
#pragma unroll
    for (int t = 0; t < 8; ++t) al[t] = *(const bf16x8*)&AsL[cur][aoff[t]];
    __builtin_amdgcn_s_setprio(1);
#pragma unroll
    for (int i = 0; i < 8; ++i)
#pragma unroll
      for (int j = 0; j < 4; ++j)
        acc[i][j] = __builtin_amdgcn_mfma_f32_16x16x32_bf16(
            ah[i], bl[j], acc[i][j], 0, 0, 0);
    __builtin_amdgcn_s_setprio(0);
    __builtin_amdgcn_s_barrier();
    CFENCE();

    // ---------------- phase C: MFMA lh = Alo x Bhi ----------------
    if (notlast) {
      GLOAD_LDS16(AgL + g0 + kn, &AsL[nxt][d0]);
      GLOAD_LDS16(AgL + g1 + kn, &AsL[nxt][d1]);
      asm volatile("s_waitcnt vmcnt(4)" ::: "memory");  // next AH,BH done (own)
    }
    __builtin_amdgcn_s_barrier();                       // all waves' AH,BH done
    CFENCE();
    // issue next-step reads: ah,bh from nxt (hidden under lh cluster).
    // old ah dead (last use phase B); old bh used by THIS cluster -> new
    // SSA values overlap its live range (+16 VGPR transient).
    if (notlast) {
#pragma unroll
      for (int t = 0; t < 8; ++t) ah[t] = *(const bf16x8*)&AsH[nxt][aoff[t]];
    }
    __builtin_amdgcn_s_setprio(1);
#pragma unroll
    for (int i = 0; i < 8; ++i)
#pragma unroll
      for (int j = 0; j < 4; ++j)
        acc[i][j] = __builtin_amdgcn_mfma_f32_16x16x32_bf16(
            al[i], bh[j], acc[i][j], 0, 0, 0);
    __builtin_amdgcn_s_setprio(0);
    if (notlast) {
#pragma unroll
      for (int t = 0; t < 4; ++t) bh[t] = *(const bf16x8*)&BsH[nxt][boff[t]];
    }
    __builtin_amdgcn_s_barrier();
    CFENCE();

    cur = nxt;
  }

  // epilogue: C/D layout col = lane&15, row = (lane>>4)*4 + reg  [m89-verified]
  float* Cp = Cpart + (size_t)split * MBN;
  const int mrow0 = tm * 256 + wm + (lane >> 4) * 4;
  const int ncol  = tn * 256 + wn + (lane & 15);
#pragma unroll
  for (int i = 0; i < 8; ++i) {
#pragma unroll
    for (int r = 0; r < 4; ++r) {
      int m = mrow0 + i * 16 + r;
      float* dst = Cp + (size_t)m * N + ncol;
#pragma unroll
      for (int j = 0; j < 4; ++j) dst[j * 16] = acc[i][j][r];
    }
  }
}

// ---------------------------------------------------------------------------
// reduce split-K partials + beta -> fp32 (intermediate layers AND final out)
__global__ __launch_bounds__(256) void reduce_f32_kernel(
    const float4* __restrict__ Cp, const float* __restrict__ beta,
    float* __restrict__ Xout, int MN4, int N4mask, int splits)
{
  int e = blockIdx.x * 256 + threadIdx.x;
  if (e >= MN4) return;
  float4 sum = Cp[e];
  for (int s = 1; s < splits; ++s) {
    float4 v = Cp[(size_t)s * MN4 + e];
    sum.x += v.x; sum.y += v.y; sum.z += v.z; sum.w += v.w;
  }
  int n0 = (e & N4mask) * 4;
  sum.x += beta[n0]; sum.y += beta[n0 + 1];
  sum.z += beta[n0 + 2]; sum.w += beta[n0 + 3];
  ((float4*)Xout)[e] = sum;
}

// ---------------------------------------------------------------------------
extern "C" void kernel_launch(void* const* d_in, const int* in_sizes, int n_in,
                              void* d_out, int out_size, void* d_ws, size_t ws_size,
                              hipStream_t stream)
{
  const float* x = (const float*)d_in[0];
  const float* coeffs[3] = {(const float*)d_in[1], (const float*)d_in[4], (const float*)d_in[7]};
  const float* alpha[3]  = {(const float*)d_in[2], (const float*)d_in[5], (const float*)d_in[8]};
  const float* beta[3]   = {(const float*)d_in[3], (const float*)d_in[6], (const float*)d_in[9]};

  const int fis[3] = {256, 512, 512};
  const int fos[3] = {512, 512, 256};
  const int trm[3] = {3, 3, 1};     // split-bf16 for layers 0,1; plain for 2

  const size_t KMAX = 67072;        // 512*131
  const size_t bsz[3] = {2ull * 512 * 33536 * 2, 2ull * 512 * 67072 * 2,
                         1ull * 256 * 67072 * 2};
  const size_t Ball   = bsz[0] + bsz[1] + bsz[2];       // 240,386,048
  const size_t B1     = 2ull * 512 * KMAX * 2;          // 137,363,456 (max single)
  const size_t needX  = 2ull * 1024 * 512 * 4;          // 4 MB

  // deterministic mode ladder from ws_size only
  int MB = 1024, allB = 0;
  size_t cbytes = 67108864;
  for (;;) {
    size_t aB = (size_t)MB * KMAX * 4;
    if (aB + Ball + needX + 67108864 <= ws_size) { allB = 1; cbytes = 67108864; break; }
    if (aB + B1 + needX + 67108864 <= ws_size)   { allB = 0; cbytes = 67108864; break; }
    if (aB + B1 + needX + 33554432 <= ws_size)   { allB = 0; cbytes = 33554432; break; }
    if (MB == 128) { allB = 0; cbytes = 33554432; break; }
    MB >>= 1;
  }
  int nchunks = 1024 / MB;

  char* ws = (char*)d_ws;
  ushort* Ahi = (ushort*)ws;
  ushort* Alo = Ahi + (size_t)MB * KMAX;
  char* Bbase = ws + (size_t)MB * KMAX * 4;
  ushort* Bh[3]; ushort* Bl[3];
  if (allB) {
    char* p = Bbase;
    for (int l = 0; l < 3; ++l) {
      Bh[l] = (ushort*)p;
      Bl[l] = (trm[l] > 1) ? (ushort*)(p + bsz[l] / 2) : (ushort*)p;
      p += bsz[l];
    }
  } else {
    for (int l = 0; l < 3; ++l) {
      Bh[l] = (ushort*)Bbase;
      Bl[l] = (trm[l] > 1) ? (ushort*)(Bbase + B1 / 2) : (ushort*)Bbase;
    }
  }
  size_t bTot = allB ? Ball : B1;
  float* X1    = (float*)(Bbase + bTot);
  float* X2    = X1 + 1024 * 512;
  float* Cpart = X2 + 1024 * 512;

  if (allB) {
    int nb0 = (33536 / 256) * 512;
    int nb1 = (67072 / 256) * 512;
    int nb2 = (67072 / 256) * 256;
    repack_all<<<nb0 + nb1 + nb2, 256, 0, stream>>>(
        coeffs[0], alpha[0], Bh[0], Bl[0],
        coeffs[1], alpha[1], Bh[1], Bl[1],
        coeffs[2], alpha[2], Bh[2],
        fos[0], fos[1], fos[2], 33536, 67072, 67072, nb0, nb0 + nb1);
  }

  const float* Xl = x;
  for (int l = 0; l < 3; ++l) {
    int fi = fis[l], fo = fos[l];
    int Kaug = fi * 131;            // 33536 / 67072 — divisible by 256
    int T = Kaug / 32;              // BK=32 steps
    int nterms = trm[l];

    if (!allB) {
      repack_kernel<<<dim3(Kaug / 256, fo), 256, 0, stream>>>(
          coeffs[l], alpha[l], Bh[l], Bl[l], fo, Kaug, nterms > 1 ? 1 : 0);
    }

    float* Xout_f = (l == 0) ? X1 : (l == 1 ? X2 : (float*)d_out);
    bool use256 = (nterms > 1) && (MB % 256 == 0) && (fo % 256 == 0);
    for (int c = 0; c < nchunks; ++c) {
      int mb0 = c * MB;
      act_kernel<<<(MB * fi) / 256, 256, 0, stream>>>(
          Xl + (size_t)mb0 * fi, Ahi, Alo, l == 0 ? 1 : 0, nterms > 1 ? 1 : 0);
      int MN4 = MB * fo / 4;
      if (use256) {
        int tilesN2 = fo / 256;
        int tiles2  = (MB / 256) * tilesN2;
        int skmem   = (int)(cbytes / 4 / ((size_t)MB * fo));
        int sk2     = 256 / tiles2;
        if (sk2 > skmem) sk2 = skmem;
        if (sk2 < 1) sk2 = 1;
        gemm256_nt3<<<tiles2 * sk2, 512, 0, stream>>>(
            Ahi, Alo, Bh[l], Bl[l], Cpart, fo, Kaug, T, sk2, tilesN2, MB * fo);
        reduce_f32_kernel<<<(MN4 + 255) / 256, 256, 0, stream>>>(
            (const float4*)Cpart, beta[l],
            Xout_f + (size_t)mb0 * fo, MN4, fo / 4 - 1, sk2);
      } else {
        int tilesN = fo / 128;
        int sk = (int)(cbytes / 4 / ((size_t)MB * fo));
        if (sk < 1) sk = 1;
        gemm_bf16_onepass<<<(MB / 128) * tilesN * sk, 256, 0, stream>>>(
            Ahi, (nterms > 1) ? Alo : Ahi, Bh[l], Bl[l],
            Cpart, fo, Kaug, T, sk, tilesN, MB * fo, nterms);
        reduce_f32_kernel<<<(MN4 + 255) / 256, 256, 0, stream>>>(
            (const float4*)Cpart, beta[l],
            Xout_f + (size_t)mb0 * fo, MN4, fo / 4 - 1, sk);
      }
    }
    Xl = Xout_f;
  }
}

// Round 4
// 989.184 us; speedup vs baseline: 1.6646x; 1.6646x over previous
//
#include <hip/hip_runtime.h>
#include <hip/hip_bf16.h>
#include <cstdint>

// sincKAN: 3 layers. B=1024, features 256->512->512->256, LEN_H=2, DEGREE+1=65.
// Kaug = fi*131 (per input i: h0 d0..64 | h1 d0..64 | skip slot = x_i).
// Split-bf16 (hi/lo): acc += Ahi*Bhi + Ahi*Blo + Alo*Bhi (layers 0,1);
// layer 2 hi-only. PASSED R8 @ 2.125 (1069us), R10 @ 2.125 (963us).
// R10: 256x256-tile 3-phase counted-vmcnt GEMM (8 waves 2Mx4N, BK=32,
// 128KiB LDS dbuf, raw s_barrier + CFENCE, setprio). 205us/L1, MfmaUtil 44%.
// R11 FAILED (1646us): hoisting frags across barriers -> spills (WRITE_SIZE
// 65->824MB). Lesson: never extend fragment live ranges across barriers.
// R12: ONE region per K-step (2 barriers, not 6; 1 vmcnt, not 3). All 8
// next-tile gloads issue at step top; vmcnt(8) guarantees cur tile; then
// all 24 ds_reads + 96 MFMA in a single barrier-free region -- compiler
// interleaves reads under MFMAs with counted lgkmcnt (m97-verified), with
// region-local fragment lifetimes (no spill). Prefetch spans a full step.
// Layer 2 keeps the proven 128x128 one-pass kernel.

#define PI_F 3.14159265358979323846f

typedef float floatx4 __attribute__((ext_vector_type(4)));
typedef __bf16 bf16x8 __attribute__((ext_vector_type(8)));

// global -> LDS direct DMA, 16B per lane (lane-contiguous dest, per m104/m108).
#define GLOAD_LDS16(gp, lp)                                                    \
  __builtin_amdgcn_global_load_lds(                                            \
      (const __attribute__((address_space(1))) void*)(uintptr_t)(const void*)(gp), \
      (__attribute__((address_space(3))) void*)(uint32_t)(uintptr_t)(void*)(lp),   \
      16, 0, 0)

// compiler-only fence: no instruction emitted, pins memory-op order across
// raw s_barrier (which is NOT an IR-level memory barrier).
#define CFENCE() asm volatile("" ::: "memory")

// ---------------------------------------------------------------------------
// repack body: coeffs (fi,fo,2,65) + alpha (fi,fo) -> Bhi/Blo (fo x Kaug)
static __device__ __forceinline__ void repack_body(
    const float* __restrict__ coeffs, const float* __restrict__ alpha,
    ushort* __restrict__ Bhi, ushort* __restrict__ Blo,
    int fo, int Kaug, int writeLo, int idx, int tid)
{
  int nchunksK = Kaug >> 8;
  int o     = idx / nchunksK;
  int chunk = idx - o * nchunksK;
  int r = chunk * 256 + tid;
  int i = r / 131;
  int j = r - i * 131;
  float v;
  if (j == 130) {
    v = alpha[(size_t)i * fo + o];
  } else {
    int h1 = (j >= 65) ? 1 : 0;
    int d  = j - (h1 ? 65 : 0);
    v = coeffs[(((size_t)i * fo + o) * 2 + h1) * 65 + d];
  }
  __hip_bfloat16 hb = __float2bfloat16(v);
  Bhi[(size_t)o * Kaug + r] = *(ushort*)&hb;
  if (writeLo) {
    __hip_bfloat16 lb = __float2bfloat16(v - __bfloat162float(hb));
    Blo[(size_t)o * Kaug + r] = *(ushort*)&lb;
  }
}

// all-3-layers repack in one dispatch (allB mode)
__global__ __launch_bounds__(256) void repack_all(
    const float* c0, const float* a0, ushort* h0, ushort* l0,
    const float* c1, const float* a1, ushort* h1, ushort* l1,
    const float* c2, const float* a2, ushort* h2,
    int fo0, int fo1, int fo2, int K0, int K1, int K2, int nb0, int nb01)
{
  int b = blockIdx.x, tid = threadIdx.x;
  if (b < nb0)        repack_body(c0, a0, h0, l0, fo0, K0, 1, b,        tid);
  else if (b < nb01)  repack_body(c1, a1, h1, l1, fo1, K1, 1, b - nb0,  tid);
  else                repack_body(c2, a2, h2, 0,  fo2, K2, 0, b - nb01, tid);
}

// per-layer repack (fallback mode)
__global__ __launch_bounds__(256) void repack_kernel(
    const float* __restrict__ coeffs, const float* __restrict__ alpha,
    ushort* __restrict__ Bhi, ushort* __restrict__ Blo,
    int fo, int Kaug, int writeLo)
{
  repack_body(coeffs, alpha, Bhi, Blo, fo, Kaug, writeLo,
              blockIdx.x + blockIdx.y * gridDim.x, threadIdx.x);
}

// ---------------------------------------------------------------------------
// act: Xin (MB x fi) fp32 -> Ahi/Alo (MB x Kaug) bf16 pair, chunk-local.
__global__ __launch_bounds__(256) void act_kernel(
    const float* __restrict__ Xin, ushort* __restrict__ Ahi,
    ushort* __restrict__ Alo, int first, int writeLo)
{
  __shared__ float sm[256][5];
  int tid = threadIdx.x;
  int p0  = blockIdx.x * 256;   // first (b,i) pair of this block (chunk-local)
  {
    float x  = Xin[p0 + tid];
    float t  = first ? tanhf(x) : x;   // layer-0 normalizer
    float xa = tanhf(t);
    float z0 = 4.0f * xa, z1 = 8.0f * xa;   // exact (pow2 scale, h=1/4,1/8)
    float n0 = rintf(z0), n1 = rintf(z1);
    float s0 = sinf(PI_F * (z0 - n0)) * (1.0f / PI_F);
    float s1 = sinf(PI_F * (z1 - n1)) * (1.0f / PI_F);
    if (((int)n0) & 1) s0 = -s0;
    if (((int)n1) & 1) s1 = -s1;
    sm[tid][0] = t;
    sm[tid][1] = z0;
    sm[tid][2] = s0;
    sm[tid][3] = z1;
    sm[tid][4] = s1;
  }
  __syncthreads();
  size_t base = (size_t)p0 * 131;           // multiple of 4 (256*131*blk)
  for (int e4 = tid; e4 < 64 * 131; e4 += 256) {   // 131*256/4 quads
    int f0 = e4 * 4;
    ushort4 hv, lv;
#pragma unroll
    for (int u = 0; u < 4; ++u) {
      int f  = f0 + u;
      int li = f / 131;
      int j  = f - li * 131;
      float t = sm[li][0];
      bool h1 = (j >= 65);
      int d   = h1 ? (j - 65) : j;
      float z = h1 ? sm[li][3] : sm[li][1];
      float s = h1 ? sm[li][4] : sm[li][2];
      int kk  = d - 32;
      float den = z + (float)kk;
      float v = __fdividef(s, den);
      if (kk & 1) v = -v;
      if (den == 0.0f) v = 1.0f;   // sinc(0) = 1 (sign: n=-kk, parity cancels)
      if (j == 130)    v = t;      // skip-connection slot
      __hip_bfloat16 hb = __float2bfloat16(v);
      __hip_bfloat16 lb = __float2bfloat16(v - __bfloat162float(hb));
      ((ushort*)&hv)[u] = *(ushort*)&hb;
      ((ushort*)&lv)[u] = *(ushort*)&lb;
    }
    *(ushort4*)(Ahi + base + f0) = hv;
    if (writeLo) *(ushort4*)(Alo + base + f0) = lv;
  }
}

// ---------------------------------------------------------------------------
// gemm one-pass 128x128 (kept for layer 2 / fallback): see R8 notes.
__global__ __launch_bounds__(256, 4) void gemm_bf16_onepass(
    const ushort* __restrict__ Ahi, const ushort* __restrict__ Alo,
    const ushort* __restrict__ Bhi, const ushort* __restrict__ Blo,
    float* __restrict__ Cpart,              // splitk x MB x N
    int N, int Kaug, int T, int splitk, int tilesN, int MBN, int nterms)
{
  __shared__ __align__(16) ushort AsH[128 * 32];
  __shared__ __align__(16) ushort AsL[128 * 32];
  __shared__ __align__(16) ushort BsH[128 * 32];
  __shared__ __align__(16) ushort BsL[128 * 32];

  int bx    = blockIdx.x;
  int split = bx % splitk;
  int tile  = bx / splitk;
  int tm = tile / tilesN;
  int tn = tile - tm * tilesN;
  int s0 = (int)(((long long)split * T) / splitk);
  int s1 = (int)(((long long)(split + 1) * T) / splitk);

  int tid  = threadIdx.x;
  int lane = tid & 63;
  int wave = tid >> 6;
  int wm = (wave >> 1) * 64;
  int wn = (wave & 1) * 64;

  floatx4 acc[4][4];
#pragma unroll
  for (int i = 0; i < 4; i++)
#pragma unroll
    for (int j = 0; j < 4; j++) acc[i][j] = floatx4{0.f, 0.f, 0.f, 0.f};

  const ushort* AgH = Ahi + (size_t)tm * 128 * Kaug;
  const ushort* AgL = Alo + (size_t)tm * 128 * Kaug;
  const ushort* BgH = Bhi + (size_t)tn * 128 * Kaug;
  const ushort* BgL = Blo + (size_t)tn * 128 * Kaug;

  int rsub = lane & 15;
  int qc   = lane >> 4;
  int aoff[4], boff[4];
#pragma unroll
  for (int t = 0; t < 4; ++t) {
    int ra = wm + t * 16 + rsub;
    aoff[t] = (ra * 4 + (qc ^ (ra & 3) ^ ((ra >> 2) & 3))) * 8;
    int rb = wn + t * 16 + rsub;
    boff[t] = (rb * 4 + (qc ^ (rb & 3) ^ ((rb >> 2) & 3))) * 8;
  }

  for (int s = s0; s < s1; ++s) {
    int k0 = s * 32;
#pragma unroll
    for (int r = 0; r < 2; ++r) {           // 512 chunks per tile, 2 iters
      int c   = tid + 256 * r;
      int row = c >> 2;
      int cc  = c & 3;
      int kcg = cc ^ (row & 3) ^ ((row >> 2) & 3);
      size_t goff = (size_t)row * Kaug + k0 + kcg * 8;
      GLOAD_LDS16(AgH + goff, &AsH[c * 8]);
      GLOAD_LDS16(BgH + goff, &BsH[c * 8]);
      if (nterms > 1) {
        GLOAD_LDS16(AgL + goff, &AsL[c * 8]);
        GLOAD_LDS16(BgL + goff, &BsL[c * 8]);
      }
    }
    __syncthreads();

    bf16x8 ah[4], bh[4];
#pragma unroll
    for (int t = 0; t < 4; ++t) ah[t] = *(const bf16x8*)&AsH[aoff[t]];
#pragma unroll
    for (int t = 0; t < 4; ++t) bh[t] = *(const bf16x8*)&BsH[boff[t]];
#pragma unroll
    for (int i = 0; i < 4; ++i)
#pragma unroll
      for (int j = 0; j < 4; ++j)
        acc[i][j] = __builtin_amdgcn_mfma_f32_16x16x32_bf16(
            ah[i], bh[j], acc[i][j], 0, 0, 0);

    if (nterms > 1) {
      bf16x8 bl[4];
#pragma unroll
      for (int t = 0; t < 4; ++t) bl[t] = *(const bf16x8*)&BsL[boff[t]];
#pragma unroll
      for (int i = 0; i < 4; ++i)
#pragma unroll
        for (int j = 0; j < 4; ++j)
          acc[i][j] = __builtin_amdgcn_mfma_f32_16x16x32_bf16(
              ah[i], bl[j], acc[i][j], 0, 0, 0);
      bf16x8 al[4];
#pragma unroll
      for (int t = 0; t < 4; ++t) al[t] = *(const bf16x8*)&AsL[aoff[t]];
#pragma unroll
      for (int i = 0; i < 4; ++i)
#pragma unroll
        for (int j = 0; j < 4; ++j)
          acc[i][j] = __builtin_amdgcn_mfma_f32_16x16x32_bf16(
              al[i], bh[j], acc[i][j], 0, 0, 0);
    }
    __syncthreads();
  }

  float* Cp = Cpart + (size_t)split * MBN;
  int mrow0 = tm * 128 + wm + (lane >> 4) * 4;
  int ncol  = tn * 128 + wn + (lane & 15);
#pragma unroll
  for (int i = 0; i < 4; ++i) {
#pragma unroll
    for (int r = 0; r < 4; ++r) {
      int m = mrow0 + i * 16 + r;
      float* dst = Cp + (size_t)m * N + ncol;
#pragma unroll
      for (int j = 0; j < 4; ++j) dst[j * 16] = acc[i][j][r];
    }
  }
}

// ---------------------------------------------------------------------------
// R12: 256x256-tile single-region counted-vmcnt GEMM for nterms=3.
// 512 threads = 8 waves (2M x 4N), per-wave 128x64 output, BK=32.
// LDS: 4 operand tiles (AH/AL/BH/BL) x 2 buffers x 16KB = 128 KiB.
// Per K-step: issue 8 gloads (next tile) -> vmcnt(8) (cur tile landed;
// never 0 mid-loop) -> barrier -> {24 ds_read + 96 MFMA, one region,
// compiler-scheduled counted lgkmcnt, region-local frag lifetimes}
// -> barrier. 2 barriers/step (R10 had 6).
__global__ __launch_bounds__(512, 2) void gemm256_nt3(
    const ushort* __restrict__ Ahi, const ushort* __restrict__ Alo,
    const ushort* __restrict__ Bhi, const ushort* __restrict__ Blo,
    float* __restrict__ Cpart,              // splitk x MB x N
    int N, int Kaug, int T, int splitk, int tilesN, int MBN)
{
  __shared__ __align__(16) ushort AsH[2][8192];
  __shared__ __align__(16) ushort AsL[2][8192];
  __shared__ __align__(16) ushort BsH[2][8192];
  __shared__ __align__(16) ushort BsL[2][8192];

  const int bx    = blockIdx.x;
  const int split = bx % splitk;            // split = bx%sk: same-split tile
  const int tile  = bx / splitk;            // group co-lands on one XCD (sk%8==0)
  const int tm = tile / tilesN;
  const int tn = tile - tm * tilesN;
  const int s0 = (int)(((long long)split * T) / splitk);
  const int s1 = (int)(((long long)(split + 1) * T) / splitk);

  const int tid  = threadIdx.x;
  const int lane = tid & 63;
  const int wave = tid >> 6;
  const int wm = (wave >> 2) * 128;
  const int wn = (wave & 3) * 64;

  floatx4 acc[8][4];
#pragma unroll
  for (int i = 0; i < 8; ++i)
#pragma unroll
    for (int j = 0; j < 4; ++j) acc[i][j] = floatx4{0.f, 0.f, 0.f, 0.f};

  const ushort* AgH = Ahi + (size_t)tm * 256 * Kaug;
  const ushort* AgL = Alo + (size_t)tm * 256 * Kaug;
  const ushort* BgH = Bhi + (size_t)tn * 256 * Kaug;
  const ushort* BgL = Blo + (size_t)tn * 256 * Kaug;

  // staging: thread covers chunks c0=tid, c1=tid+512 of 1024 16B-chunks per
  // operand tile. LDS dest linear (lane-contiguous); global source
  // pre-swizzled with x(row) = (row&3)^((row>>2)&3)  (proven in R8 kernel).
  const int c0 = tid, c1 = tid + 512;
  const int r0c = c0 >> 2, q0c = c0 & 3;
  const int r1c = c1 >> 2, q1c = c1 & 3;
  const size_t g0 = (size_t)r0c * Kaug + (size_t)((q0c ^ (r0c & 3) ^ ((r0c >> 2) & 3)) * 8);
  const size_t g1 = (size_t)r1c * Kaug + (size_t)((q1c ^ (r1c & 3) ^ ((r1c >> 2) & 3)) * 8);
  const int d0 = c0 * 8, d1 = c1 * 8;       // LDS ushort offsets

  // MFMA fragment LDS offsets (ushort units): row ra, k-chunk qc, swizzled.
  const int rsub = lane & 15;
  const int qc   = lane >> 4;
  int aoff[8], boff[4];
#pragma unroll
  for (int t = 0; t < 8; ++t) {
    int ra = wm + t * 16 + rsub;
    aoff[t] = (ra * 4 + (qc ^ (ra & 3) ^ ((ra >> 2) & 3))) * 8;
  }
#pragma unroll
  for (int t = 0; t < 4; ++t) {
    int rb = wn + t * 16 + rsub;
    boff[t] = (rb * 4 + (qc ^ (rb & 3) ^ ((rb >> 2) & 3))) * 8;
  }

  { // prologue: stage tile s0 into buffer 0 (no wait here; loop waits)
    const int k0 = s0 * 32;
    GLOAD_LDS16(AgH + g0 + k0, &AsH[0][d0]);
    GLOAD_LDS16(AgH + g1 + k0, &AsH[0][d1]);
    GLOAD_LDS16(BgH + g0 + k0, &BsH[0][d0]);
    GLOAD_LDS16(BgH + g1 + k0, &BsH[0][d1]);
    GLOAD_LDS16(BgL + g0 + k0, &BsL[0][d0]);
    GLOAD_LDS16(BgL + g1 + k0, &BsL[0][d1]);
    GLOAD_LDS16(AgL + g0 + k0, &AsL[0][d0]);
    GLOAD_LDS16(AgL + g1 + k0, &AsL[0][d1]);
  }

  int cur = 0;
  for (int s = s0; s < s1; ++s) {
    const int  nxt     = cur ^ 1;
    const bool notlast = (s + 1 < s1);
    const int  kn      = (s + 1) * 32;

    // stage next tile; counted wait guarantees CURRENT tile landed.
    if (notlast) {
      GLOAD_LDS16(AgH + g0 + kn, &AsH[nxt][d0]);
      GLOAD_LDS16(AgH + g1 + kn, &AsH[nxt][d1]);
      GLOAD_LDS16(BgH + g0 + kn, &BsH[nxt][d0]);
      GLOAD_LDS16(BgH + g1 + kn, &BsH[nxt][d1]);
      GLOAD_LDS16(BgL + g0 + kn, &BsL[nxt][d0]);
      GLOAD_LDS16(BgL + g1 + kn, &BsL[nxt][d1]);
      GLOAD_LDS16(AgL + g0 + kn, &AsL[nxt][d0]);
      GLOAD_LDS16(AgL + g1 + kn, &AsL[nxt][d1]);
      asm volatile("s_waitcnt vmcnt(8)" ::: "memory");  // cur tile done (own)
    } else {
      asm volatile("s_waitcnt vmcnt(0)" ::: "memory");  // cur tile done (tail)
    }
    __builtin_amdgcn_s_barrier();                       // ... for ALL waves
    CFENCE();

    // one region: 24 ds_read_b128 + 96 MFMA, no barriers inside.
    // Compiler interleaves reads under MFMAs (counted lgkmcnt), frag
    // lifetimes are region-local -> no cross-barrier pressure.
    {
      bf16x8 ah[8], bh[4];
#pragma unroll
      for (int t = 0; t < 4; ++t) bh[t] = *(const bf16x8*)&BsH[cur][boff[t]];
#pragma unroll
      for (int t = 0; t < 8; ++t) ah[t] = *(const bf16x8*)&AsH[cur][aoff[t]];
      __builtin_amdgcn_s_setprio(1);
#pragma unroll
      for (int i = 0; i < 8; ++i)
#pragma unroll
        for (int j = 0; j < 4; ++j)
          acc[i][j] = __builtin_amdgcn_mfma_f32_16x16x32_bf16(
              ah[i], bh[j], acc[i][j], 0, 0, 0);
      __builtin_amdgcn_s_setprio(0);

      bf16x8 bl[4];
#pragma unroll
      for (int t = 0; t < 4; ++t) bl[t] = *(const bf16x8*)&BsL[cur][boff[t]];
      __builtin_amdgcn_s_setprio(1);
#pragma unroll
      for (int i = 0; i < 8; ++i)
#pragma unroll
        for (int j = 0; j < 4; ++j)
          acc[i][j] = __builtin_amdgcn_mfma_f32_16x16x32_bf16(
              ah[i], bl[j], acc[i][j], 0, 0, 0);
      __builtin_amdgcn_s_setprio(0);

      bf16x8 al[8];
#pragma unroll
      for (int t = 0; t < 8; ++t) al[t] = *(const bf16x8*)&AsL[cur][aoff[t]];
      __builtin_amdgcn_s_setprio(1);
#pragma unroll
      for (int i = 0; i < 8; ++i)
#pragma unroll
        for (int j = 0; j < 4; ++j)
          acc[i][j] = __builtin_amdgcn_mfma_f32_16x16x32_bf16(
              al[i], bh[j], acc[i][j], 0, 0, 0);
      __builtin_amdgcn_s_setprio(0);
    }
    __builtin_amdgcn_s_barrier();   // all waves done reading cur before it
    CFENCE();                       // becomes the next prefetch target
    cur = nxt;
  }

  // epilogue: C/D layout col = lane&15, row = (lane>>4)*4 + reg  [m89-verified]
  float* Cp = Cpart + (size_t)split * MBN;
  const int mrow0 = tm * 256 + wm + (lane >> 4) * 4;
  const int ncol  = tn * 256 + wn + (lane & 15);
#pragma unroll
  for (int i = 0; i < 8; ++i) {
#pragma unroll
    for (int r = 0; r < 4; ++r) {
      int m = mrow0 + i * 16 + r;
      float* dst = Cp + (size_t)m * N + ncol;
#pragma unroll
      for (int j = 0; j < 4; ++j) dst[j * 16] = acc[i][j][r];
    }
  }
}

// ---------------------------------------------------------------------------
// reduce split-K partials + beta -> fp32 (intermediate layers AND final out)
__global__ __launch_bounds__(256) void reduce_f32_kernel(
    const float4* __restrict__ Cp, const float* __restrict__ beta,
    float* __restrict__ Xout, int MN4, int N4mask, int splits)
{
  int e = blockIdx.x * 256 + threadIdx.x;
  if (e >= MN4) return;
  float4 sum = Cp[e];
  for (int s = 1; s < splits; ++s) {
    float4 v = Cp[(size_t)s * MN4 + e];
    sum.x += v.x; sum.y += v.y; sum.z += v.z; sum.w += v.w;
  }
  int n0 = (e & N4mask) * 4;
  sum.x += beta[n0]; sum.y += beta[n0 + 1];
  sum.z += beta[n0 + 2]; sum.w += beta[n0 + 3];
  ((float4*)Xout)[e] = sum;
}

// ---------------------------------------------------------------------------
extern "C" void kernel_launch(void* const* d_in, const int* in_sizes, int n_in,
                              void* d_out, int out_size, void* d_ws, size_t ws_size,
                              hipStream_t stream)
{
  const float* x = (const float*)d_in[0];
  const float* coeffs[3] = {(const float*)d_in[1], (const float*)d_in[4], (const float*)d_in[7]};
  const float* alpha[3]  = {(const float*)d_in[2], (const float*)d_in[5], (const float*)d_in[8]};
  const float* beta[3]   = {(const float*)d_in[3], (const float*)d_in[6], (const float*)d_in[9]};

  const int fis[3] = {256, 512, 512};
  const int fos[3] = {512, 512, 256};
  const int trm[3] = {3, 3, 1};     // split-bf16 for layers 0,1; plain for 2

  const size_t KMAX = 67072;        // 512*131
  const size_t bsz[3] = {2ull * 512 * 33536 * 2, 2ull * 512 * 67072 * 2,
                         1ull * 256 * 67072 * 2};
  const size_t Ball   = bsz[0] + bsz[1] + bsz[2];       // 240,386,048
  const size_t B1     = 2ull * 512 * KMAX * 2;          // 137,363,456 (max single)
  const size_t needX  = 2ull * 1024 * 512 * 4;          // 4 MB

  // deterministic mode ladder from ws_size only
  int MB = 1024, allB = 0;
  size_t cbytes = 67108864;
  for (;;) {
    size_t aB = (size_t)MB * KMAX * 4;
    if (aB + Ball + needX + 67108864 <= ws_size) { allB = 1; cbytes = 67108864; break; }
    if (aB + B1 + needX + 67108864 <= ws_size)   { allB = 0; cbytes = 67108864; break; }
    if (aB + B1 + needX + 33554432 <= ws_size)   { allB = 0; cbytes = 33554432; break; }
    if (MB == 128) { allB = 0; cbytes = 33554432; break; }
    MB >>= 1;
  }
  int nchunks = 1024 / MB;

  char* ws = (char*)d_ws;
  ushort* Ahi = (ushort*)ws;
  ushort* Alo = Ahi + (size_t)MB * KMAX;
  char* Bbase = ws + (size_t)MB * KMAX * 4;
  ushort* Bh[3]; ushort* Bl[3];
  if (allB) {
    char* p = Bbase;
    for (int l = 0; l < 3; ++l) {
      Bh[l] = (ushort*)p;
      Bl[l] = (trm[l] > 1) ? (ushort*)(p + bsz[l] / 2) : (ushort*)p;
      p += bsz[l];
    }
  } else {
    for (int l = 0; l < 3; ++l) {
      Bh[l] = (ushort*)Bbase;
      Bl[l] = (trm[l] > 1) ? (ushort*)(Bbase + B1 / 2) : (ushort*)Bbase;
    }
  }
  size_t bTot = allB ? Ball : B1;
  float* X1    = (float*)(Bbase + bTot);
  float* X2    = X1 + 1024 * 512;
  float* Cpart = X2 + 1024 * 512;

  if (allB) {
    int nb0 = (33536 / 256) * 512;
    int nb1 = (67072 / 256) * 512;
    int nb2 = (67072 / 256) * 256;
    repack_all<<<nb0 + nb1 + nb2, 256, 0, stream>>>(
        coeffs[0], alpha[0], Bh[0], Bl[0],
        coeffs[1], alpha[1], Bh[1], Bl[1],
        coeffs[2], alpha[2], Bh[2],
        fos[0], fos[1], fos[2], 33536, 67072, 67072, nb0, nb0 + nb1);
  }

  const float* Xl = x;
  for (int l = 0; l < 3; ++l) {
    int fi = fis[l], fo = fos[l];
    int Kaug = fi * 131;            // 33536 / 67072 — divisible by 256
    int T = Kaug / 32;              // BK=32 steps
    int nterms = trm[l];

    if (!allB) {
      repack_kernel<<<dim3(Kaug / 256, fo), 256, 0, stream>>>(
          coeffs[l], alpha[l], Bh[l], Bl[l], fo, Kaug, nterms > 1 ? 1 : 0);
    }

    float* Xout_f = (l == 0) ? X1 : (l == 1 ? X2 : (float*)d_out);
    bool use256 = (nterms > 1) && (MB % 256 == 0) && (fo % 256 == 0);
    for (int c = 0; c < nchunks; ++c) {
      int mb0 = c * MB;
      act_kernel<<<(MB * fi) / 256, 256, 0, stream>>>(
          Xl + (size_t)mb0 * fi, Ahi, Alo, l == 0 ? 1 : 0, nterms > 1 ? 1 : 0);
      int MN4 = MB * fo / 4;
      if (use256) {
        int tilesN2 = fo / 256;
        int tiles2  = (MB / 256) * tilesN2;
        int skmem   = (int)(cbytes / 4 / ((size_t)MB * fo));
        int sk2     = 256 / tiles2;
        if (sk2 > skmem) sk2 = skmem;
        if (sk2 < 1) sk2 = 1;
        gemm256_nt3<<<tiles2 * sk2, 512, 0, stream>>>(
            Ahi, Alo, Bh[l], Bl[l], Cpart, fo, Kaug, T, sk2, tilesN2, MB * fo);
        reduce_f32_kernel<<<(MN4 + 255) / 256, 256, 0, stream>>>(
            (const float4*)Cpart, beta[l],
            Xout_f + (size_t)mb0 * fo, MN4, fo / 4 - 1, sk2);
      } else {
        int tilesN = fo / 128;
        int sk = (int)(cbytes / 4 / ((size_t)MB * fo));
        if (sk < 1) sk = 1;
        gemm_bf16_onepass<<<(MB / 128) * tilesN * sk, 256, 0, stream>>>(
            Ahi, (nterms > 1) ? Alo : Ahi, Bh[l], Bl[l],
            Cpart, fo, Kaug, T, sk, tilesN, MB * fo, nterms);
        reduce_f32_kernel<<<(MN4 + 255) / 256, 256, 0, stream>>>(
            (const float4*)Cpart, beta[l],
            Xout_f + (size_t)mb0 * fo, MN4, fo / 4 - 1, sk);
      }
    }
    Xl = Xout_f;
  }
}

// Round 5
// 942.993 us; speedup vs baseline: 1.7461x; 1.0490x over previous
//
#include <hip/hip_runtime.h>
#include <hip/hip_bf16.h>
#include <cstdint>

// sincKAN: 3 layers. B=1024, features 256->512->512->256, LEN_H=2, DEGREE+1=65.
// Kaug = fi*131 (per input i: h0 d0..64 | h1 d0..64 | skip slot = x_i).
// Split-bf16 (hi/lo): acc += Ahi*Bhi + Ahi*Blo + Alo*Bhi (layers 0,1);
// layer 2 hi-only. PASSED R8 @ 2.125 (1069us), R10 @ 2.125 (963us), R12 (989us).
// R10 (3-phase, reads-after-barrier): 205us/L1, MfmaUtil 44%.
// R11 FAILED: frags hoisted across barriers -> spills (WRITE 65->824MB).
// R12 (1-region/step): 226us, 39% -- pipes SUM, not overlap: reads sit
// after the data barrier, immediately ahead of their MFMA cluster; all 8
// waves lockstep -> LDS idle during MFMA, matrix idle during read bursts.
// R13: m201-shape 6-phase step. Each phase: {ds_reads issued EARLY (before
// the phase barrier, data guaranteed by an EARLIER wait+barrier) | 2 gloads
// | counted vmcnt one phase before first use | barrier | 16-MFMA cluster}.
// Reads fly during barrier-wait + previous cluster's pipe drain. B-quad
// lives across one barrier (16 VGPR); A-frags re-read (36 reads/step).
// vmcnt: ph2(6) cur-BL, ph4(6) cur-AL, ph6(4) next-AH/BH; tail 2/0/none.
// Same hh->hl->lh accumulation order as R10/R12 (bit-compatible).
// Layer 2 keeps the proven 128x128 one-pass kernel.

#define PI_F 3.14159265358979323846f

typedef float floatx4 __attribute__((ext_vector_type(4)));
typedef __bf16 bf16x8 __attribute__((ext_vector_type(8)));

// global -> LDS direct DMA, 16B per lane (lane-contiguous dest, per m104/m108).
#define GLOAD_LDS16(gp, lp)                                                    \
  __builtin_amdgcn_global_load_lds(                                            \
      (const __attribute__((address_space(1))) void*)(uintptr_t)(const void*)(gp), \
      (__attribute__((address_space(3))) void*)(uint32_t)(uintptr_t)(void*)(lp),   \
      16, 0, 0)

// compiler-only fence: no instruction emitted, pins memory-op order across
// raw s_barrier (which is NOT an IR-level memory barrier).
#define CFENCE() asm volatile("" ::: "memory")

// ---------------------------------------------------------------------------
// repack body: coeffs (fi,fo,2,65) + alpha (fi,fo) -> Bhi/Blo (fo x Kaug)
static __device__ __forceinline__ void repack_body(
    const float* __restrict__ coeffs, const float* __restrict__ alpha,
    ushort* __restrict__ Bhi, ushort* __restrict__ Blo,
    int fo, int Kaug, int writeLo, int idx, int tid)
{
  int nchunksK = Kaug >> 8;
  int o     = idx / nchunksK;
  int chunk = idx - o * nchunksK;
  int r = chunk * 256 + tid;
  int i = r / 131;
  int j = r - i * 131;
  float v;
  if (j == 130) {
    v = alpha[(size_t)i * fo + o];
  } else {
    int h1 = (j >= 65) ? 1 : 0;
    int d  = j - (h1 ? 65 : 0);
    v = coeffs[(((size_t)i * fo + o) * 2 + h1) * 65 + d];
  }
  __hip_bfloat16 hb = __float2bfloat16(v);
  Bhi[(size_t)o * Kaug + r] = *(ushort*)&hb;
  if (writeLo) {
    __hip_bfloat16 lb = __float2bfloat16(v - __bfloat162float(hb));
    Blo[(size_t)o * Kaug + r] = *(ushort*)&lb;
  }
}

// all-3-layers repack in one dispatch (allB mode)
__global__ __launch_bounds__(256) void repack_all(
    const float* c0, const float* a0, ushort* h0, ushort* l0,
    const float* c1, const float* a1, ushort* h1, ushort* l1,
    const float* c2, const float* a2, ushort* h2,
    int fo0, int fo1, int fo2, int K0, int K1, int K2, int nb0, int nb01)
{
  int b = blockIdx.x, tid = threadIdx.x;
  if (b < nb0)        repack_body(c0, a0, h0, l0, fo0, K0, 1, b,        tid);
  else if (b < nb01)  repack_body(c1, a1, h1, l1, fo1, K1, 1, b - nb0,  tid);
  else                repack_body(c2, a2, h2, 0,  fo2, K2, 0, b - nb01, tid);
}

// per-layer repack (fallback mode)
__global__ __launch_bounds__(256) void repack_kernel(
    const float* __restrict__ coeffs, const float* __restrict__ alpha,
    ushort* __restrict__ Bhi, ushort* __restrict__ Blo,
    int fo, int Kaug, int writeLo)
{
  repack_body(coeffs, alpha, Bhi, Blo, fo, Kaug, writeLo,
              blockIdx.x + blockIdx.y * gridDim.x, threadIdx.x);
}

// ---------------------------------------------------------------------------
// act: Xin (MB x fi) fp32 -> Ahi/Alo (MB x Kaug) bf16 pair, chunk-local.
__global__ __launch_bounds__(256) void act_kernel(
    const float* __restrict__ Xin, ushort* __restrict__ Ahi,
    ushort* __restrict__ Alo, int first, int writeLo)
{
  __shared__ float sm[256][5];
  int tid = threadIdx.x;
  int p0  = blockIdx.x * 256;   // first (b,i) pair of this block (chunk-local)
  {
    float x  = Xin[p0 + tid];
    float t  = first ? tanhf(x) : x;   // layer-0 normalizer
    float xa = tanhf(t);
    float z0 = 4.0f * xa, z1 = 8.0f * xa;   // exact (pow2 scale, h=1/4,1/8)
    float n0 = rintf(z0), n1 = rintf(z1);
    float s0 = sinf(PI_F * (z0 - n0)) * (1.0f / PI_F);
    float s1 = sinf(PI_F * (z1 - n1)) * (1.0f / PI_F);
    if (((int)n0) & 1) s0 = -s0;
    if (((int)n1) & 1) s1 = -s1;
    sm[tid][0] = t;
    sm[tid][1] = z0;
    sm[tid][2] = s0;
    sm[tid][3] = z1;
    sm[tid][4] = s1;
  }
  __syncthreads();
  size_t base = (size_t)p0 * 131;           // multiple of 4 (256*131*blk)
  for (int e4 = tid; e4 < 64 * 131; e4 += 256) {   // 131*256/4 quads
    int f0 = e4 * 4;
    ushort4 hv, lv;
#pragma unroll
    for (int u = 0; u < 4; ++u) {
      int f  = f0 + u;
      int li = f / 131;
      int j  = f - li * 131;
      float t = sm[li][0];
      bool h1 = (j >= 65);
      int d   = h1 ? (j - 65) : j;
      float z = h1 ? sm[li][3] : sm[li][1];
      float s = h1 ? sm[li][4] : sm[li][2];
      int kk  = d - 32;
      float den = z + (float)kk;
      float v = __fdividef(s, den);
      if (kk & 1) v = -v;
      if (den == 0.0f) v = 1.0f;   // sinc(0) = 1 (sign: n=-kk, parity cancels)
      if (j == 130)    v = t;      // skip-connection slot
      __hip_bfloat16 hb = __float2bfloat16(v);
      __hip_bfloat16 lb = __float2bfloat16(v - __bfloat162float(hb));
      ((ushort*)&hv)[u] = *(ushort*)&hb;
      ((ushort*)&lv)[u] = *(ushort*)&lb;
    }
    *(ushort4*)(Ahi + base + f0) = hv;
    if (writeLo) *(ushort4*)(Alo + base + f0) = lv;
  }
}

// ---------------------------------------------------------------------------
// gemm one-pass 128x128 (kept for layer 2 / fallback): see R8 notes.
__global__ __launch_bounds__(256, 4) void gemm_bf16_onepass(
    const ushort* __restrict__ Ahi, const ushort* __restrict__ Alo,
    const ushort* __restrict__ Bhi, const ushort* __restrict__ Blo,
    float* __restrict__ Cpart,              // splitk x MB x N
    int N, int Kaug, int T, int splitk, int tilesN, int MBN, int nterms)
{
  __shared__ __align__(16) ushort AsH[128 * 32];
  __shared__ __align__(16) ushort AsL[128 * 32];
  __shared__ __align__(16) ushort BsH[128 * 32];
  __shared__ __align__(16) ushort BsL[128 * 32];

  int bx    = blockIdx.x;
  int split = bx % splitk;
  int tile  = bx / splitk;
  int tm = tile / tilesN;
  int tn = tile - tm * tilesN;
  int s0 = (int)(((long long)split * T) / splitk);
  int s1 = (int)(((long long)(split + 1) * T) / splitk);

  int tid  = threadIdx.x;
  int lane = tid & 63;
  int wave = tid >> 6;
  int wm = (wave >> 1) * 64;
  int wn = (wave & 1) * 64;

  floatx4 acc[4][4];
#pragma unroll
  for (int i = 0; i < 4; i++)
#pragma unroll
    for (int j = 0; j < 4; j++) acc[i][j] = floatx4{0.f, 0.f, 0.f, 0.f};

  const ushort* AgH = Ahi + (size_t)tm * 128 * Kaug;
  const ushort* AgL = Alo + (size_t)tm * 128 * Kaug;
  const ushort* BgH = Bhi + (size_t)tn * 128 * Kaug;
  const ushort* BgL = Blo + (size_t)tn * 128 * Kaug;

  int rsub = lane & 15;
  int qc   = lane >> 4;
  int aoff[4], boff[4];
#pragma unroll
  for (int t = 0; t < 4; ++t) {
    int ra = wm + t * 16 + rsub;
    aoff[t] = (ra * 4 + (qc ^ (ra & 3) ^ ((ra >> 2) & 3))) * 8;
    int rb = wn + t * 16 + rsub;
    boff[t] = (rb * 4 + (qc ^ (rb & 3) ^ ((rb >> 2) & 3))) * 8;
  }

  for (int s = s0; s < s1; ++s) {
    int k0 = s * 32;
#pragma unroll
    for (int r = 0; r < 2; ++r) {           // 512 chunks per tile, 2 iters
      int c   = tid + 256 * r;
      int row = c >> 2;
      int cc  = c & 3;
      int kcg = cc ^ (row & 3) ^ ((row >> 2) & 3);
      size_t goff = (size_t)row * Kaug + k0 + kcg * 8;
      GLOAD_LDS16(AgH + goff, &AsH[c * 8]);
      GLOAD_LDS16(BgH + goff, &BsH[c * 8]);
      if (nterms > 1) {
        GLOAD_LDS16(AgL + goff, &AsL[c * 8]);
        GLOAD_LDS16(BgL + goff, &BsL[c * 8]);
      }
    }
    __syncthreads();

    bf16x8 ah[4], bh[4];
#pragma unroll
    for (int t = 0; t < 4; ++t) ah[t] = *(const bf16x8*)&AsH[aoff[t]];
#pragma unroll
    for (int t = 0; t < 4; ++t) bh[t] = *(const bf16x8*)&BsH[boff[t]];
#pragma unroll
    for (int i = 0; i < 4; ++i)
#pragma unroll
      for (int j = 0; j < 4; ++j)
        acc[i][j] = __builtin_amdgcn_mfma_f32_16x16x32_bf16(
            ah[i], bh[j], acc[i][j], 0, 0, 0);

    if (nterms > 1) {
      bf16x8 bl[4];
#pragma unroll
      for (int t = 0; t < 4; ++t) bl[t] = *(const bf16x8*)&BsL[boff[t]];
#pragma unroll
      for (int i = 0; i < 4; ++i)
#pragma unroll
        for (int j = 0; j < 4; ++j)
          acc[i][j] = __builtin_amdgcn_mfma_f32_16x16x32_bf16(
              ah[i], bl[j], acc[i][j], 0, 0, 0);
      bf16x8 al[4];
#pragma unroll
      for (int t = 0; t < 4; ++t) al[t] = *(const bf16x8*)&AsL[aoff[t]];
#pragma unroll
      for (int i = 0; i < 4; ++i)
#pragma unroll
        for (int j = 0; j < 4; ++j)
          acc[i][j] = __builtin_amdgcn_mfma_f32_16x16x32_bf16(
              al[i], bh[j], acc[i][j], 0, 0, 0);
    }
    __syncthreads();
  }

  float* Cp = Cpart + (size_t)split * MBN;
  int mrow0 = tm * 128 + wm + (lane >> 4) * 4;
  int ncol  = tn * 128 + wn + (lane & 15);
#pragma unroll
  for (int i = 0; i < 4; ++i) {
#pragma unroll
    for (int r = 0; r < 4; ++r) {
      int m = mrow0 + i * 16 + r;
      float* dst = Cp + (size_t)m * N + ncol;
#pragma unroll
      for (int j = 0; j < 4; ++j) dst[j * 16] = acc[i][j][r];
    }
  }
}

// ---------------------------------------------------------------------------
// R13: 256x256-tile 6-phase GEMM for nterms=3 (m201 shape).
// 512 threads = 8 waves (2M x 4N), per-wave 128x64 output, BK=32.
// LDS: 4 operand tiles (AH/AL/BH/BL) x 2 buffers x 16KB = 128 KiB.
// Phases (16 MFMA each): 1 hh-lo | 2 hh-hi | 3 hl-lo | 4 hl-hi | 5 lh-lo |
// 6 lh-hi. Reads early-in-phase; barrier mid-phase; MFMA after. Gloads:
// ph1 AHn, ph2 BHn, ph3 BLn, ph5 ALn. vmcnt: ph2(6/2), ph4(6/0), ph6(4/-).
__global__ __launch_bounds__(512, 2) void gemm256_nt3(
    const ushort* __restrict__ Ahi, const ushort* __restrict__ Alo,
    const ushort* __restrict__ Bhi, const ushort* __restrict__ Blo,
    float* __restrict__ Cpart,              // splitk x MB x N
    int N, int Kaug, int T, int splitk, int tilesN, int MBN)
{
  __shared__ __align__(16) ushort AsH[2][8192];
  __shared__ __align__(16) ushort AsL[2][8192];
  __shared__ __align__(16) ushort BsH[2][8192];
  __shared__ __align__(16) ushort BsL[2][8192];

  const int bx    = blockIdx.x;
  const int split = bx % splitk;            // split = bx%sk: same-split tile
  const int tile  = bx / splitk;            // group co-lands on one XCD (sk%8==0)
  const int tm = tile / tilesN;
  const int tn = tile - tm * tilesN;
  const int s0 = (int)(((long long)split * T) / splitk);
  const int s1 = (int)(((long long)(split + 1) * T) / splitk);

  const int tid  = threadIdx.x;
  const int lane = tid & 63;
  const int wave = tid >> 6;
  const int wm = (wave >> 2) * 128;
  const int wn = (wave & 3) * 64;

  floatx4 acc[8][4];
#pragma unroll
  for (int i = 0; i < 8; ++i)
#pragma unroll
    for (int j = 0; j < 4; ++j) acc[i][j] = floatx4{0.f, 0.f, 0.f, 0.f};

  const ushort* AgH = Ahi + (size_t)tm * 256 * Kaug;
  const ushort* AgL = Alo + (size_t)tm * 256 * Kaug;
  const ushort* BgH = Bhi + (size_t)tn * 256 * Kaug;
  const ushort* BgL = Blo + (size_t)tn * 256 * Kaug;

  // staging: thread covers chunks c0=tid, c1=tid+512 of 1024 16B-chunks per
  // operand tile. LDS dest linear (lane-contiguous); global source
  // pre-swizzled with x(row) = (row&3)^((row>>2)&3)  (proven in R8 kernel).
  const int c0 = tid, c1 = tid + 512;
  const int r0c = c0 >> 2, q0c = c0 & 3;
  const int r1c = c1 >> 2, q1c = c1 & 3;
  const size_t g0 = (size_t)r0c * Kaug + (size_t)((q0c ^ (r0c & 3) ^ ((r0c >> 2) & 3)) * 8);
  const size_t g1 = (size_t)r1c * Kaug + (size_t)((q1c ^ (r1c & 3) ^ ((r1c >> 2) & 3)) * 8);
  const int d0 = c0 * 8, d1 = c1 * 8;       // LDS ushort offsets

  // MFMA fragment LDS offsets (ushort units): row ra, k-chunk qc, swizzled.
  const int rsub = lane & 15;
  const int qc   = lane >> 4;
  int aoff[8], boff[4];
#pragma unroll
  for (int t = 0; t < 8; ++t) {
    int ra = wm + t * 16 + rsub;
    aoff[t] = (ra * 4 + (qc ^ (ra & 3) ^ ((ra >> 2) & 3))) * 8;
  }
#pragma unroll
  for (int t = 0; t < 4; ++t) {
    int rb = wn + t * 16 + rsub;
    boff[t] = (rb * 4 + (qc ^ (rb & 3) ^ ((rb >> 2) & 3))) * 8;
  }

  { // prologue: stage tile s0 into buffer 0 (order AH,AH,BH,BH,BL,BL,AL,AL)
    const int k0 = s0 * 32;
    GLOAD_LDS16(AgH + g0 + k0, &AsH[0][d0]);
    GLOAD_LDS16(AgH + g1 + k0, &AsH[0][d1]);
    GLOAD_LDS16(BgH + g0 + k0, &BsH[0][d0]);
    GLOAD_LDS16(BgH + g1 + k0, &BsH[0][d1]);
    GLOAD_LDS16(BgL + g0 + k0, &BsL[0][d0]);
    GLOAD_LDS16(BgL + g1 + k0, &BsL[0][d1]);
    GLOAD_LDS16(AgL + g0 + k0, &AsL[0][d0]);
    GLOAD_LDS16(AgL + g1 + k0, &AsL[0][d1]);
  }
  asm volatile("s_waitcnt vmcnt(4)" ::: "memory");   // AH,BH landed (own)
  __builtin_amdgcn_s_barrier();                      // ... for ALL waves
  CFENCE();                                          // 4 outstanding: BL,AL

  int cur = 0;
  for (int s = s0; s < s1; ++s) {
    const int  nxt     = cur ^ 1;
    const bool notlast = (s + 1 < s1);
    const int  kn      = (s + 1) * 32;
    bf16x8 bq[4];                  // B quad: lives across ONE barrier (pair)

    // ---- ph1: hh-lo  acc[0..3] += ah03 x bh ----
    {
      bf16x8 f[4];
#pragma unroll
      for (int t = 0; t < 4; ++t) bq[t] = *(const bf16x8*)&BsH[cur][boff[t]];
#pragma unroll
      for (int t = 0; t < 4; ++t) f[t] = *(const bf16x8*)&AsH[cur][aoff[t]];
      if (notlast) {
        GLOAD_LDS16(AgH + g0 + kn, &AsH[nxt][d0]);
        GLOAD_LDS16(AgH + g1 + kn, &AsH[nxt][d1]);
      }
      CFENCE();
      __builtin_amdgcn_s_barrier();
      CFENCE();
      __builtin_amdgcn_s_setprio(1);
#pragma unroll
      for (int i = 0; i < 4; ++i)
#pragma unroll
        for (int j = 0; j < 4; ++j)
          acc[i][j] = __builtin_amdgcn_mfma_f32_16x16x32_bf16(
              f[i], bq[j], acc[i][j], 0, 0, 0);
      __builtin_amdgcn_s_setprio(0);
    }

    // ---- ph2: hh-hi  acc[4..7] += ah47 x bh ----
    {
      bf16x8 f[4];
#pragma unroll
      for (int t = 0; t < 4; ++t) f[t] = *(const bf16x8*)&AsH[cur][aoff[4 + t]];
      if (notlast) {
        GLOAD_LDS16(BgH + g0 + kn, &BsH[nxt][d0]);
        GLOAD_LDS16(BgH + g1 + kn, &BsH[nxt][d1]);
        asm volatile("s_waitcnt vmcnt(6)" ::: "memory");  // cur BL landed
      } else {
        asm volatile("s_waitcnt vmcnt(2)" ::: "memory");
      }
      __builtin_amdgcn_s_barrier();
      CFENCE();
      __builtin_amdgcn_s_setprio(1);
#pragma unroll
      for (int i = 0; i < 4; ++i)
#pragma unroll
        for (int j = 0; j < 4; ++j)
          acc[4 + i][j] = __builtin_amdgcn_mfma_f32_16x16x32_bf16(
              f[i], bq[j], acc[4 + i][j], 0, 0, 0);
      __builtin_amdgcn_s_setprio(0);
    }

    // ---- ph3: hl-lo  acc[0..3] += ah03 x bl ----
    {
      bf16x8 f[4];
#pragma unroll
      for (int t = 0; t < 4; ++t) bq[t] = *(const bf16x8*)&BsL[cur][boff[t]];
#pragma unroll
      for (int t = 0; t < 4; ++t) f[t] = *(const bf16x8*)&AsH[cur][aoff[t]];
      if (notlast) {
        GLOAD_LDS16(BgL + g0 + kn, &BsL[nxt][d0]);
        GLOAD_LDS16(BgL + g1 + kn, &BsL[nxt][d1]);
      }
      CFENCE();
      __builtin_amdgcn_s_barrier();
      CFENCE();
      __builtin_amdgcn_s_setprio(1);
#pragma unroll
      for (int i = 0; i < 4; ++i)
#pragma unroll
        for (int j = 0; j < 4; ++j)
          acc[i][j] = __builtin_amdgcn_mfma_f32_16x16x32_bf16(
              f[i], bq[j], acc[i][j], 0, 0, 0);
      __builtin_amdgcn_s_setprio(0);
    }

    // ---- ph4: hl-hi  acc[4..7] += ah47 x bl ----
    {
      bf16x8 f[4];
#pragma unroll
      for (int t = 0; t < 4; ++t) f[t] = *(const bf16x8*)&AsH[cur][aoff[4 + t]];
      if (notlast) {
        asm volatile("s_waitcnt vmcnt(6)" ::: "memory");  // cur AL landed
      } else {
        asm volatile("s_waitcnt vmcnt(0)" ::: "memory");
      }
      __builtin_amdgcn_s_barrier();
      CFENCE();
      __builtin_amdgcn_s_setprio(1);
#pragma unroll
      for (int i = 0; i < 4; ++i)
#pragma unroll
        for (int j = 0; j < 4; ++j)
          acc[4 + i][j] = __builtin_amdgcn_mfma_f32_16x16x32_bf16(
              f[i], bq[j], acc[4 + i][j], 0, 0, 0);
      __builtin_amdgcn_s_setprio(0);
    }

    // ---- ph5: lh-lo  acc[0..3] += al03 x bh ----
    {
      bf16x8 f[4];
#pragma unroll
      for (int t = 0; t < 4; ++t) bq[t] = *(const bf16x8*)&BsH[cur][boff[t]];
#pragma unroll
      for (int t = 0; t < 4; ++t) f[t] = *(const bf16x8*)&AsL[cur][aoff[t]];
      if (notlast) {
        GLOAD_LDS16(AgL + g0 + kn, &AsL[nxt][d0]);
        GLOAD_LDS16(AgL + g1 + kn, &AsL[nxt][d1]);
      }
      CFENCE();
      __builtin_amdgcn_s_barrier();
      CFENCE();
      __builtin_amdgcn_s_setprio(1);
#pragma unroll
      for (int i = 0; i < 4; ++i)
#pragma unroll
        for (int j = 0; j < 4; ++j)
          acc[i][j] = __builtin_amdgcn_mfma_f32_16x16x32_bf16(
              f[i], bq[j], acc[i][j], 0, 0, 0);
      __builtin_amdgcn_s_setprio(0);
    }

    // ---- ph6: lh-hi  acc[4..7] += al47 x bh ----
    {
      bf16x8 f[4];
#pragma unroll
      for (int t = 0; t < 4; ++t) f[t] = *(const bf16x8*)&AsL[cur][aoff[4 + t]];
      if (notlast) {
        asm volatile("s_waitcnt vmcnt(4)" ::: "memory");  // next AH,BH landed
      } else {
        CFENCE();
      }
      __builtin_amdgcn_s_barrier();
      CFENCE();
      __builtin_amdgcn_s_setprio(1);
#pragma unroll
      for (int i = 0; i < 4; ++i)
#pragma unroll
        for (int j = 0; j < 4; ++j)
          acc[4 + i][j] = __builtin_amdgcn_mfma_f32_16x16x32_bf16(
              f[i], bq[j], acc[4 + i][j], 0, 0, 0);
      __builtin_amdgcn_s_setprio(0);
    }

    cur = nxt;
  }

  // epilogue: C/D layout col = lane&15, row = (lane>>4)*4 + reg  [m89-verified]
  float* Cp = Cpart + (size_t)split * MBN;
  const int mrow0 = tm * 256 + wm + (lane >> 4) * 4;
  const int ncol  = tn * 256 + wn + (lane & 15);
#pragma unroll
  for (int i = 0; i < 8; ++i) {
#pragma unroll
    for (int r = 0; r < 4; ++r) {
      int m = mrow0 + i * 16 + r;
      float* dst = Cp + (size_t)m * N + ncol;
#pragma unroll
      for (int j = 0; j < 4; ++j) dst[j * 16] = acc[i][j][r];
    }
  }
}

// ---------------------------------------------------------------------------
// reduce split-K partials + beta -> fp32 (intermediate layers AND final out)
__global__ __launch_bounds__(256) void reduce_f32_kernel(
    const float4* __restrict__ Cp, const float* __restrict__ beta,
    float* __restrict__ Xout, int MN4, int N4mask, int splits)
{
  int e = blockIdx.x * 256 + threadIdx.x;
  if (e >= MN4) return;
  float4 sum = Cp[e];
  for (int s = 1; s < splits; ++s) {
    float4 v = Cp[(size_t)s * MN4 + e];
    sum.x += v.x; sum.y += v.y; sum.z += v.z; sum.w += v.w;
  }
  int n0 = (e & N4mask) * 4;
  sum.x += beta[n0]; sum.y += beta[n0 + 1];
  sum.z += beta[n0 + 2]; sum.w += beta[n0 + 3];
  ((float4*)Xout)[e] = sum;
}

// ---------------------------------------------------------------------------
extern "C" void kernel_launch(void* const* d_in, const int* in_sizes, int n_in,
                              void* d_out, int out_size, void* d_ws, size_t ws_size,
                              hipStream_t stream)
{
  const float* x = (const float*)d_in[0];
  const float* coeffs[3] = {(const float*)d_in[1], (const float*)d_in[4], (const float*)d_in[7]};
  const float* alpha[3]  = {(const float*)d_in[2], (const float*)d_in[5], (const float*)d_in[8]};
  const float* beta[3]   = {(const float*)d_in[3], (const float*)d_in[6], (const float*)d_in[9]};

  const int fis[3] = {256, 512, 512};
  const int fos[3] = {512, 512, 256};
  const int trm[3] = {3, 3, 1};     // split-bf16 for layers 0,1; plain for 2

  const size_t KMAX = 67072;        // 512*131
  const size_t bsz[3] = {2ull * 512 * 33536 * 2, 2ull * 512 * 67072 * 2,
                         1ull * 256 * 67072 * 2};
  const size_t Ball   = bsz[0] + bsz[1] + bsz[2];       // 240,386,048
  const size_t B1     = 2ull * 512 * KMAX * 2;          // 137,363,456 (max single)
  const size_t needX  = 2ull * 1024 * 512 * 4;          // 4 MB

  // deterministic mode ladder from ws_size only
  int MB = 1024, allB = 0;
  size_t cbytes = 67108864;
  for (;;) {
    size_t aB = (size_t)MB * KMAX * 4;
    if (aB + Ball + needX + 67108864 <= ws_size) { allB = 1; cbytes = 67108864; break; }
    if (aB + B1 + needX + 67108864 <= ws_size)   { allB = 0; cbytes = 67108864; break; }
    if (aB + B1 + needX + 33554432 <= ws_size)   { allB = 0; cbytes = 33554432; break; }
    if (MB == 128) { allB = 0; cbytes = 33554432; break; }
    MB >>= 1;
  }
  int nchunks = 1024 / MB;

  char* ws = (char*)d_ws;
  ushort* Ahi = (ushort*)ws;
  ushort* Alo = Ahi + (size_t)MB * KMAX;
  char* Bbase = ws + (size_t)MB * KMAX * 4;
  ushort* Bh[3]; ushort* Bl[3];
  if (allB) {
    char* p = Bbase;
    for (int l = 0; l < 3; ++l) {
      Bh[l] = (ushort*)p;
      Bl[l] = (trm[l] > 1) ? (ushort*)(p + bsz[l] / 2) : (ushort*)p;
      p += bsz[l];
    }
  } else {
    for (int l = 0; l < 3; ++l) {
      Bh[l] = (ushort*)Bbase;
      Bl[l] = (trm[l] > 1) ? (ushort*)(Bbase + B1 / 2) : (ushort*)Bbase;
    }
  }
  size_t bTot = allB ? Ball : B1;
  float* X1    = (float*)(Bbase + bTot);
  float* X2    = X1 + 1024 * 512;
  float* Cpart = X2 + 1024 * 512;

  if (allB) {
    int nb0 = (33536 / 256) * 512;
    int nb1 = (67072 / 256) * 512;
    int nb2 = (67072 / 256) * 256;
    repack_all<<<nb0 + nb1 + nb2, 256, 0, stream>>>(
        coeffs[0], alpha[0], Bh[0], Bl[0],
        coeffs[1], alpha[1], Bh[1], Bl[1],
        coeffs[2], alpha[2], Bh[2],
        fos[0], fos[1], fos[2], 33536, 67072, 67072, nb0, nb0 + nb1);
  }

  const float* Xl = x;
  for (int l = 0; l < 3; ++l) {
    int fi = fis[l], fo = fos[l];
    int Kaug = fi * 131;            // 33536 / 67072 — divisible by 256
    int T = Kaug / 32;              // BK=32 steps
    int nterms = trm[l];

    if (!allB) {
      repack_kernel<<<dim3(Kaug / 256, fo), 256, 0, stream>>>(
          coeffs[l], alpha[l], Bh[l], Bl[l], fo, Kaug, nterms > 1 ? 1 : 0);
    }

    float* Xout_f = (l == 0) ? X1 : (l == 1 ? X2 : (float*)d_out);
    bool use256 = (nterms > 1) && (MB % 256 == 0) && (fo % 256 == 0);
    for (int c = 0; c < nchunks; ++c) {
      int mb0 = c * MB;
      act_kernel<<<(MB * fi) / 256, 256, 0, stream>>>(
          Xl + (size_t)mb0 * fi, Ahi, Alo, l == 0 ? 1 : 0, nterms > 1 ? 1 : 0);
      int MN4 = MB * fo / 4;
      if (use256) {
        int tilesN2 = fo / 256;
        int tiles2  = (MB / 256) * tilesN2;
        int skmem   = (int)(cbytes / 4 / ((size_t)MB * fo));
        int sk2     = 256 / tiles2;
        if (sk2 > skmem) sk2 = skmem;
        if (sk2 < 1) sk2 = 1;
        gemm256_nt3<<<tiles2 * sk2, 512, 0, stream>>>(
            Ahi, Alo, Bh[l], Bl[l], Cpart, fo, Kaug, T, sk2, tilesN2, MB * fo);
        reduce_f32_kernel<<<(MN4 + 255) / 256, 256, 0, stream>>>(
            (const float4*)Cpart, beta[l],
            Xout_f + (size_t)mb0 * fo, MN4, fo / 4 - 1, sk2);
      } else {
        int tilesN = fo / 128;
        int sk = (int)(cbytes / 4 / ((size_t)MB * fo));
        if (sk < 1) sk = 1;
        gemm_bf16_onepass<<<(MB / 128) * tilesN * sk, 256, 0, stream>>>(
            Ahi, (nterms > 1) ? Alo : Ahi, Bh[l], Bl[l],
            Cpart, fo, Kaug, T, sk, tilesN, MB * fo, nterms);
        reduce_f32_kernel<<<(MN4 + 255) / 256, 256, 0, stream>>>(
            (const float4*)Cpart, beta[l],
            Xout_f + (size_t)mb0 * fo, MN4, fo / 4 - 1, sk);
      }
    }
    Xl = Xout_f;
  }
}